// Round 6
// baseline (329.652 us; speedup 1.0000x reference)
//
#include <hip/hip_runtime.h>
#include <hip/hip_bf16.h>

typedef __attribute__((ext_vector_type(8))) short short8;
typedef __attribute__((ext_vector_type(4))) float f32x4;
typedef unsigned short ushort_t;

#define NTOK 262144   // B*D*H*W = 2*32*64*64

__device__ __forceinline__ ushort_t f2bf(float f){
  unsigned int x = __float_as_uint(f);
  unsigned int r = (x + 0x7fffu + ((x >> 16) & 1u)) >> 16;
  return (ushort_t)r;
}
// exact-erf gelu via Abramowitz-Stegun 7.1.26 (|err| <= 1.5e-7), branch-free
__device__ __forceinline__ float gelu_exact(float x){
  float u = fabsf(x) * 0.70710678118654752440f;
  float t = 1.0f / (1.0f + 0.3275911f * u);
  float poly = t * (0.254829592f + t * (-0.284496736f + t * (1.421413741f +
               t * (-1.453152027f + t * 1.061405429f))));
  float e = __expf(-u * u);
  float er = copysignf(1.0f - poly * e, x);
  return 0.5f * x * (1.0f + er);
}

// ---------------- weight prep: fp32 -> bf16, transposed to Bt[col][k] ----------------
__global__ __launch_bounds__(256) void prep_kernel(
    const float* __restrict__ wq, const float* __restrict__ wk, const float* __restrict__ wv,
    const float* __restrict__ wo, const float* __restrict__ w1, const float* __restrict__ w2,
    const float* __restrict__ bq, const float* __restrict__ bk, const float* __restrict__ bv,
    ushort_t* __restrict__ Wqkv, ushort_t* __restrict__ Wo,
    ushort_t* __restrict__ W1, ushort_t* __restrict__ W2, float* __restrict__ biasq)
{
  int i = blockIdx.x * 256 + threadIdx.x;
  if (i < 27648) {                       // Wqkv_t[j][c], j = s*96 + h*24 + d
    int j = i / 96, c = i % 96;
    int s = j / 96, rem = j % 96;
    const float* src = (s == 0) ? wq : (s == 1) ? wk : wv;
    Wqkv[j * 96 + c] = f2bf(src[c * 96 + rem]);
  } else if (i < 36864) {                // Wo_t[c][hd] = wo[hd][c]
    int ii = i - 27648;
    int c = ii / 96, hd = ii % 96;
    Wo[ii] = f2bf(wo[hd * 96 + c]);
  } else if (i < 73728) {                // W1_t[j][c] = w1[c][j]
    int ii = i - 36864;
    int j = ii / 96, c = ii % 96;
    W1[ii] = f2bf(w1[c * 384 + j]);
  } else if (i < 110592) {               // W2_t[c][j] = w2[j][c]
    int ii = i - 73728;
    int c = ii / 384, j = ii % 384;
    W2[ii] = f2bf(w2[j * 96 + c]);
  } else if (i < 110880) {               // combined qkv bias (fp32)
    int j = i - 110592;
    int s = j / 96, rem = j % 96;
    const float* src = (s == 0) ? bq : (s == 1) ? bk : bv;
    biasq[j] = src[rem];
  }
}

// ---- per-thread half-row LN into LDS tile smem[128][104] (bf16) ----
// thread t: row t>>1, channels (t&1)*48..+47. Rows w*32..w*32+31 are written
// ONLY by wave w -> all smem traffic in lnqkv/mlp2 is wave-private (no barriers).
__device__ __forceinline__ void ln_to_lds(const float* __restrict__ xrow_base,
    const float* __restrict__ gg, const float* __restrict__ bb,
    ushort_t (*hbt)[104], int tid)
{
  int row = tid >> 1, half = tid & 1;
  const float* xp = xrow_base + (size_t)row * 96 + half * 48;
  f32x4 v[12];
  float s = 0.f, sq = 0.f;
  #pragma unroll
  for (int i = 0; i < 12; i++) {
    v[i] = *reinterpret_cast<const f32x4*>(xp + i * 4);
    #pragma unroll
    for (int j = 0; j < 4; j++) { s += v[i][j]; sq += v[i][j] * v[i][j]; }
  }
  s  += __shfl_xor(s, 1);
  sq += __shfl_xor(sq, 1);
  float mean = s * (1.0f / 96.0f);
  float var  = sq * (1.0f / 96.0f) - mean * mean;
  float rstd = rsqrtf(var + 1e-5f);
  #pragma unroll
  for (int i8 = 0; i8 < 6; i8++) {
    short8 pk;
    #pragma unroll
    for (int j = 0; j < 8; j++) {
      int c = half * 48 + i8 * 8 + j;
      pk[j] = (short)f2bf((v[(i8 * 8 + j) >> 2][(i8 * 8 + j) & 3] - mean) * rstd * gg[c] + bb[c]);
    }
    *reinterpret_cast<short8*>(&hbt[row][half * 48 + i8 * 8]) = pk;
  }
}

// ---------------- fused LN1 + QKV projection ----------------
// block = 128 rows, 4 independent waves x (2 m-tiles). No barriers (wave-private LDS).
__global__ __launch_bounds__(256, 3) void lnqkv_kernel(const float* __restrict__ x,
    const float* __restrict__ g, const float* __restrict__ b,
    const ushort_t* __restrict__ Wt, const float* __restrict__ biasq,
    ushort_t* __restrict__ qkv)
{
  __shared__ ushort_t hbt[128][104];
  int tid = threadIdx.x;
  size_t r0 = (size_t)blockIdx.x * 128;
  ln_to_lds(x + r0 * 96, g, b, hbt, tid);

  int w = tid >> 6, lane = tid & 63, g16 = lane >> 4, l15 = lane & 15;
  short8 af[2][3];
  #pragma unroll
  for (int mi = 0; mi < 2; mi++)
    #pragma unroll
    for (int ks = 0; ks < 3; ks++)
      af[mi][ks] = *reinterpret_cast<const short8*>(&hbt[w * 32 + mi * 16 + l15][ks * 32 + g16 * 8]);

  #pragma unroll
  for (int grp = 0; grp < 3; grp++) {
    short8 wf[18];
    #pragma unroll
    for (int j = 0; j < 6; j++)
      #pragma unroll
      for (int ks = 0; ks < 3; ks++)
        wf[j * 3 + ks] = *reinterpret_cast<const short8*>(
            &Wt[(size_t)((grp * 6 + j) * 16 + l15) * 96 + ks * 32 + g16 * 8]);
    f32x4 acc[2][6];
    #pragma unroll
    for (int mi = 0; mi < 2; mi++)
      #pragma unroll
      for (int j = 0; j < 6; j++) acc[mi][j] = (f32x4){0.f, 0.f, 0.f, 0.f};
    #pragma unroll
    for (int j = 0; j < 6; j++)
      #pragma unroll
      for (int ks = 0; ks < 3; ks++) {
        acc[0][j] = __builtin_amdgcn_mfma_f32_16x16x32_bf16(af[0][ks], wf[j * 3 + ks], acc[0][j], 0, 0, 0);
        acc[1][j] = __builtin_amdgcn_mfma_f32_16x16x32_bf16(af[1][ks], wf[j * 3 + ks], acc[1][j], 0, 0, 0);
      }
    #pragma unroll
    for (int j = 0; j < 6; j++) {
      int col = (grp * 6 + j) * 16 + l15;
      float bs = biasq[col];
      #pragma unroll
      for (int mi = 0; mi < 2; mi++)
        #pragma unroll
        for (int r = 0; r < 4; r++)
          qkv[(r0 + w * 32 + mi * 16 + g16 * 4 + r) * 288 + col] = f2bf(acc[mi][j][r] + bs);
    }
  }
}

// ---------------- fused window attention + output projection ----------------
__global__ __launch_bounds__(256) void attn2_kernel(
    const ushort_t* __restrict__ qkv, const ushort_t* __restrict__ Wot,
    const float* __restrict__ bo, const float* __restrict__ xres,
    float* __restrict__ x2)
{
  __shared__ ushort_t Pb[4][64][72];   // P[q][k'] per head
  __shared__ ushort_t Vt[4][32][72];   // V^T[d][k'] per head
  ushort_t (*O_lds)[104] = reinterpret_cast<ushort_t (*)[104]>(&Pb[0][0][0]); // aliases Pb

  int tid = threadIdx.x;
  int h = tid >> 6, lane = tid & 63, g = lane >> 4, l15 = lane & 15;
  int n = blockIdx.x;
  int wq_ = n & 15, hq = (n >> 4) & 15, rest = n >> 8;
  int dq = rest & 7, b = rest >> 3;
  int base = b * 131072 + dq * 16384 + hq * 256 + wq_ * 4;
  #define TOK(s) (base + ((s) >> 4) * 4096 + (((s) >> 2) & 3) * 64 + ((s) & 3))

  {
    int t = TOK(lane);
    const ushort_t* vp = qkv + (size_t)t * 288 + 192 + h * 24;
    short8 v0 = *(const short8*)(vp);
    short8 v1 = *(const short8*)(vp + 8);
    short8 v2 = *(const short8*)(vp + 16);
    #pragma unroll
    for (int d = 0; d < 8; d++) Vt[h][d][lane]      = (ushort_t)v0[d];
    #pragma unroll
    for (int d = 0; d < 8; d++) Vt[h][8 + d][lane]  = (ushort_t)v1[d];
    #pragma unroll
    for (int d = 0; d < 8; d++) Vt[h][16 + d][lane] = (ushort_t)v2[d];
  }

  short8 kf[4], qf[4];
  const short8 z8 = {0, 0, 0, 0, 0, 0, 0, 0};
  #pragma unroll
  for (int i = 0; i < 4; i++) {
    int t = TOK(i * 16 + l15);
    const ushort_t* rp = qkv + (size_t)t * 288 + h * 24 + g * 8;
    qf[i] = (g < 3) ? *(const short8*)(rp)      : z8;
    kf[i] = (g < 3) ? *(const short8*)(rp + 96) : z8;
  }

  f32x4 st[4][4];
  #pragma unroll
  for (int tm = 0; tm < 4; tm++)
    #pragma unroll
    for (int tn = 0; tn < 4; tn++)
      st[tm][tn] = __builtin_amdgcn_mfma_f32_16x16x32_bf16(kf[tm], qf[tn],
                    (f32x4){0.f, 0.f, 0.f, 0.f}, 0, 0, 0);

  const float scale = 0.20412414523193150818f;  // 1/sqrt(24)
  #pragma unroll
  for (int tn = 0; tn < 4; tn++) {
    float m = st[0][tn][0];
    #pragma unroll
    for (int tm = 0; tm < 4; tm++)
      #pragma unroll
      for (int r = 0; r < 4; r++) m = fmaxf(m, st[tm][tn][r]);
    m = fmaxf(m, __shfl_xor(m, 16));
    m = fmaxf(m, __shfl_xor(m, 32));
    float sum = 0.f;
    #pragma unroll
    for (int tm = 0; tm < 4; tm++)
      #pragma unroll
      for (int r = 0; r < 4; r++) {
        float e = __expf((st[tm][tn][r] - m) * scale);
        st[tm][tn][r] = e;
        sum += e;
      }
    sum += __shfl_xor(sum, 16);
    sum += __shfl_xor(sum, 32);
    float inv = 1.0f / sum;
    int q = tn * 16 + l15;
    #pragma unroll
    for (int tm = 0; tm < 4; tm++) {
      unsigned lo = (unsigned)f2bf(st[tm][tn][0] * inv) | ((unsigned)f2bf(st[tm][tn][1] * inv) << 16);
      unsigned hi = (unsigned)f2bf(st[tm][tn][2] * inv) | ((unsigned)f2bf(st[tm][tn][3] * inv) << 16);
      uint2 pk; pk.x = lo; pk.y = hi;
      *(uint2*)&Pb[h][q][tm * 16 + g * 4] = pk;
    }
  }

  f32x4 oacc[4][2];
  #pragma unroll
  for (int qt = 0; qt < 4; qt++)
    #pragma unroll
    for (int dt = 0; dt < 2; dt++) oacc[qt][dt] = (f32x4){0.f, 0.f, 0.f, 0.f};
  #pragma unroll
  for (int ks = 0; ks < 2; ks++) {
    short8 vb[2];
    #pragma unroll
    for (int dt = 0; dt < 2; dt++)
      vb[dt] = *(const short8*)&Vt[h][dt * 16 + l15][ks * 32 + g * 8];
    #pragma unroll
    for (int qt = 0; qt < 4; qt++) {
      short8 pa = *(const short8*)&Pb[h][qt * 16 + l15][ks * 32 + g * 8];
      #pragma unroll
      for (int dt = 0; dt < 2; dt++)
        oacc[qt][dt] = __builtin_amdgcn_mfma_f32_16x16x32_bf16(pa, vb[dt], oacc[qt][dt], 0, 0, 0);
    }
  }

  __syncthreads();
  #pragma unroll
  for (int qt = 0; qt < 4; qt++)
    #pragma unroll
    for (int dt = 0; dt < 2; dt++) {
      int d = dt * 16 + l15;
      if (d < 24) {
        #pragma unroll
        for (int r = 0; r < 4; r++)
          O_lds[qt * 16 + g * 4 + r][h * 24 + d] = f2bf(oacc[qt][dt][r]);
      }
    }
  __syncthreads();

  int w = h;
  f32x4 pacc[6];
  #pragma unroll
  for (int nt = 0; nt < 6; nt++) pacc[nt] = (f32x4){0.f, 0.f, 0.f, 0.f};
  #pragma unroll
  for (int ks = 0; ks < 3; ks++) {
    short8 pa = *(const short8*)&O_lds[w * 16 + l15][ks * 32 + g * 8];
    #pragma unroll
    for (int nt = 0; nt < 6; nt++) {
      short8 wb = *(const short8*)&Wot[(size_t)(nt * 16 + l15) * 96 + ks * 32 + g * 8];
      pacc[nt] = __builtin_amdgcn_mfma_f32_16x16x32_bf16(pa, wb, pacc[nt], 0, 0, 0);
    }
  }
  #pragma unroll
  for (int nt = 0; nt < 6; nt++) {
    int col = nt * 16 + l15;
    float bs = bo[col];
    #pragma unroll
    for (int r = 0; r < 4; r++) {
      int s = w * 16 + g * 4 + r;
      size_t t = (size_t)TOK(s);
      float v = pacc[nt][r] + bs + xres[t * 96 + col];
      x2[t * 96 + col] = v;
    }
  }
  #undef TOK
}

// ---------------- fused LN2 + MLP + residual ----------------
// block = 128 rows, 4 INDEPENDENT waves (all LDS traffic wave-private: wave w
// owns rows w*32..w*32+31 of smem). No barriers; mid aliases the LN buffer
// (af frags are in registers before the first mid write; per-wave DS ops are
// in-order). LDS 26.6 KB, 3 blocks/CU.
__global__ __launch_bounds__(256, 3) void mlp2_kernel(
    const float* __restrict__ x2, const float* __restrict__ g, const float* __restrict__ b,
    const ushort_t* __restrict__ W1t, const float* __restrict__ b1,
    const ushort_t* __restrict__ W2t, const float* __restrict__ b2,
    float* __restrict__ out)
{
  __shared__ ushort_t smem[128][104];   // LN rows, then mid (same storage)
  int tid = threadIdx.x;
  size_t r0 = (size_t)blockIdx.x * 128;
  ln_to_lds(x2 + r0 * 96, g, b, smem, tid);

  int w = tid >> 6, lane = tid & 63, g16 = lane >> 4, l15 = lane & 15;
  short8 af[2][3];
  #pragma unroll
  for (int mi = 0; mi < 2; mi++)
    #pragma unroll
    for (int ks = 0; ks < 3; ks++)
      af[mi][ks] = *reinterpret_cast<const short8*>(&smem[w * 32 + mi * 16 + l15][ks * 32 + g16 * 8]);

  f32x4 oacc[2][6];
  #pragma unroll
  for (int mi = 0; mi < 2; mi++)
    #pragma unroll
    for (int nt = 0; nt < 6; nt++) oacc[mi][nt] = (f32x4){0.f, 0.f, 0.f, 0.f};

  #pragma unroll
  for (int cc = 0; cc < 4; cc++) {
    // ---- bulk-load W1 chunk frags ----
    short8 w1f[18];
    #pragma unroll
    for (int j = 0; j < 6; j++)
      #pragma unroll
      for (int ks = 0; ks < 3; ks++)
        w1f[j * 3 + ks] = *reinterpret_cast<const short8*>(
            &W1t[(size_t)(cc * 96 + j * 16 + l15) * 96 + ks * 32 + g16 * 8]);
    // ---- phase 1 MFMAs ----
    f32x4 acc[2][6];
    #pragma unroll
    for (int mi = 0; mi < 2; mi++)
      #pragma unroll
      for (int j = 0; j < 6; j++) acc[mi][j] = (f32x4){0.f, 0.f, 0.f, 0.f};
    #pragma unroll
    for (int j = 0; j < 6; j++)
      #pragma unroll
      for (int ks = 0; ks < 3; ks++) {
        acc[0][j] = __builtin_amdgcn_mfma_f32_16x16x32_bf16(af[0][ks], w1f[j * 3 + ks], acc[0][j], 0, 0, 0);
        acc[1][j] = __builtin_amdgcn_mfma_f32_16x16x32_bf16(af[1][ks], w1f[j * 3 + ks], acc[1][j], 0, 0, 0);
      }
    // ---- issue W2 chunk loads now (fly across the gelu phase) ----
    short8 w2f[18];
    #pragma unroll
    for (int j = 0; j < 6; j++)
      #pragma unroll
      for (int ks = 0; ks < 3; ks++)
        w2f[j * 3 + ks] = *reinterpret_cast<const short8*>(
            &W2t[(size_t)(j * 16 + l15) * 384 + cc * 96 + ks * 32 + g16 * 8]);
    // ---- gelu + pack to mid (wave-private rows; in-order vs af reads) ----
    #pragma unroll
    for (int j = 0; j < 6; j++) {
      int colg = cc * 96 + j * 16 + l15;
      float bs = b1[colg];
      #pragma unroll
      for (int mi = 0; mi < 2; mi++)
        #pragma unroll
        for (int r = 0; r < 4; r++)
          smem[w * 32 + mi * 16 + g16 * 4 + r][j * 16 + l15] = f2bf(gelu_exact(acc[mi][j][r] + bs));
    }
    // ---- read mid frags (per-wave in-order LDS: sees this wave's writes) ----
    short8 a2[2][3];
    #pragma unroll
    for (int mi = 0; mi < 2; mi++)
      #pragma unroll
      for (int ks = 0; ks < 3; ks++)
        a2[mi][ks] = *reinterpret_cast<const short8*>(&smem[w * 32 + mi * 16 + l15][ks * 32 + g16 * 8]);
    // ---- phase 2 MFMAs ----
    #pragma unroll
    for (int j = 0; j < 6; j++)
      #pragma unroll
      for (int ks = 0; ks < 3; ks++) {
        oacc[0][j] = __builtin_amdgcn_mfma_f32_16x16x32_bf16(a2[0][ks], w2f[j * 3 + ks], oacc[0][j], 0, 0, 0);
        oacc[1][j] = __builtin_amdgcn_mfma_f32_16x16x32_bf16(a2[1][ks], w2f[j * 3 + ks], oacc[1][j], 0, 0, 0);
      }
  }

  // epilogue: out = oacc + b2 + residual(x2)
  #pragma unroll
  for (int j = 0; j < 6; j++) {
    int col = j * 16 + l15;
    float bs = b2[col];
    #pragma unroll
    for (int mi = 0; mi < 2; mi++)
      #pragma unroll
      for (int r = 0; r < 4; r++) {
        size_t row = r0 + w * 32 + mi * 16 + g16 * 4 + r;
        out[row * 96 + col] = oacc[mi][j][r] + bs + x2[row * 96 + col];
      }
  }
}

// ---------------- launch ----------------
extern "C" void kernel_launch(void* const* d_in, const int* in_sizes, int n_in,
                              void* d_out, int out_size, void* d_ws, size_t ws_size,
                              hipStream_t stream)
{
  (void)in_sizes; (void)n_in; (void)out_size; (void)ws_size;
  const float* x    = (const float*)d_in[0];
  const float* ln1g = (const float*)d_in[1];
  const float* ln1b = (const float*)d_in[2];
  const float* wq   = (const float*)d_in[3];
  const float* bq   = (const float*)d_in[4];
  const float* wk   = (const float*)d_in[5];
  const float* bk   = (const float*)d_in[6];
  const float* wv   = (const float*)d_in[7];
  const float* bv   = (const float*)d_in[8];
  const float* wo   = (const float*)d_in[9];
  const float* bo   = (const float*)d_in[10];
  const float* ln2g = (const float*)d_in[11];
  const float* ln2b = (const float*)d_in[12];
  const float* w1   = (const float*)d_in[13];
  const float* b1   = (const float*)d_in[14];
  const float* w2   = (const float*)d_in[15];
  const float* b2   = (const float*)d_in[16];

  char* ws = (char*)d_ws;
  ushort_t* qkv  = (ushort_t*)(ws);                          // [N,288] bf16  150,994,944 B
  char* wsw      = ws + 150994944;
  ushort_t* Wqkv = (ushort_t*)(wsw);                         // [288][96]
  ushort_t* Wo   = (ushort_t*)(wsw + 55296);                 // [96][96]
  ushort_t* W1   = (ushort_t*)(wsw + 55296 + 18432);         // [384][96]
  ushort_t* W2   = (ushort_t*)(wsw + 55296 + 18432 + 73728); // [96][384]
  float*    biasq= (float*)   (wsw + 55296 + 18432 + 73728 + 73728); // [288] fp32
  float* x2 = (float*)d_out;   // post-attention residual lives in d_out

  prep_kernel<<<434, 256, 0, stream>>>(wq, wk, wv, wo, w1, w2, bq, bk, bv,
                                       Wqkv, Wo, W1, W2, biasq);
  lnqkv_kernel<<<NTOK / 128, 256, 0, stream>>>(x, ln1g, ln1b, Wqkv, biasq, qkv);
  attn2_kernel<<<4096, 256, 0, stream>>>(qkv, Wo, bo, x, x2);
  mlp2_kernel<<<NTOK / 128, 256, 0, stream>>>(x2, ln2g, ln2b, W1, b1, W2, b2, (float*)d_out);
}

// Round 7
// 319.978 us; speedup vs baseline: 1.0302x; 1.0302x over previous
//
#include <hip/hip_runtime.h>
#include <hip/hip_bf16.h>

typedef __attribute__((ext_vector_type(8))) short short8;
typedef __attribute__((ext_vector_type(4))) float f32x4;
typedef unsigned short ushort_t;

#define NTOK 262144   // B*D*H*W = 2*32*64*64

__device__ __forceinline__ ushort_t f2bf(float f){
  unsigned int x = __float_as_uint(f);
  unsigned int r = (x + 0x7fffu + ((x >> 16) & 1u)) >> 16;
  return (ushort_t)r;
}
// exact-erf gelu via Abramowitz-Stegun 7.1.26 (|err| <= 1.5e-7), branch-free
__device__ __forceinline__ float gelu_exact(float x){
  float u = fabsf(x) * 0.70710678118654752440f;
  float t = 1.0f / (1.0f + 0.3275911f * u);
  float poly = t * (0.254829592f + t * (-0.284496736f + t * (1.421413741f +
               t * (-1.453152027f + t * 1.061405429f))));
  float e = __expf(-u * u);
  float er = copysignf(1.0f - poly * e, x);
  return 0.5f * x * (1.0f + er);
}

// ---------------- weight prep: fp32 -> bf16, transposed to Bt[col][k] ----------------
__global__ __launch_bounds__(256) void prep_kernel(
    const float* __restrict__ wq, const float* __restrict__ wk, const float* __restrict__ wv,
    const float* __restrict__ wo, const float* __restrict__ w1, const float* __restrict__ w2,
    const float* __restrict__ bq, const float* __restrict__ bk, const float* __restrict__ bv,
    ushort_t* __restrict__ Wqkv, ushort_t* __restrict__ Wo,
    ushort_t* __restrict__ W1, ushort_t* __restrict__ W2, float* __restrict__ biasq)
{
  int i = blockIdx.x * 256 + threadIdx.x;
  if (i < 27648) {                       // Wqkv_t[j][c], j = s*96 + h*24 + d
    int j = i / 96, c = i % 96;
    int s = j / 96, rem = j % 96;
    const float* src = (s == 0) ? wq : (s == 1) ? wk : wv;
    Wqkv[j * 96 + c] = f2bf(src[c * 96 + rem]);
  } else if (i < 36864) {                // Wo_t[c][hd] = wo[hd][c]
    int ii = i - 27648;
    int c = ii / 96, hd = ii % 96;
    Wo[ii] = f2bf(wo[hd * 96 + c]);
  } else if (i < 73728) {                // W1_t[j][c] = w1[c][j]
    int ii = i - 36864;
    int j = ii / 96, c = ii % 96;
    W1[ii] = f2bf(w1[c * 384 + j]);
  } else if (i < 110592) {               // W2_t[c][j] = w2[j][c]
    int ii = i - 73728;
    int c = ii / 384, j = ii % 384;
    W2[ii] = f2bf(w2[j * 96 + c]);
  } else if (i < 110880) {               // combined qkv bias (fp32)
    int j = i - 110592;
    int s = j / 96, rem = j % 96;
    const float* src = (s == 0) ? bq : (s == 1) ? bk : bv;
    biasq[j] = src[rem];
  }
}

// ---- per-thread half-row LN into LDS tile smem[128][104] (bf16) ----
// thread t: row t>>1, channels (t&1)*48..+47. Rows w*32..w*32+31 are written
// ONLY by wave w -> all smem traffic in lnqkv/mlp2 is wave-private (no barriers).
__device__ __forceinline__ void ln_to_lds(const float* __restrict__ xrow_base,
    const float* __restrict__ gg, const float* __restrict__ bb,
    ushort_t (*hbt)[104], int tid)
{
  int row = tid >> 1, half = tid & 1;
  const float* xp = xrow_base + (size_t)row * 96 + half * 48;
  f32x4 v[12];
  float s = 0.f, sq = 0.f;
  #pragma unroll
  for (int i = 0; i < 12; i++) {
    v[i] = *reinterpret_cast<const f32x4*>(xp + i * 4);
    #pragma unroll
    for (int j = 0; j < 4; j++) { s += v[i][j]; sq += v[i][j] * v[i][j]; }
  }
  s  += __shfl_xor(s, 1);
  sq += __shfl_xor(sq, 1);
  float mean = s * (1.0f / 96.0f);
  float var  = sq * (1.0f / 96.0f) - mean * mean;
  float rstd = rsqrtf(var + 1e-5f);
  #pragma unroll
  for (int i8 = 0; i8 < 6; i8++) {
    short8 pk;
    #pragma unroll
    for (int j = 0; j < 8; j++) {
      int c = half * 48 + i8 * 8 + j;
      pk[j] = (short)f2bf((v[(i8 * 8 + j) >> 2][(i8 * 8 + j) & 3] - mean) * rstd * gg[c] + bb[c]);
    }
    *reinterpret_cast<short8*>(&hbt[row][half * 48 + i8 * 8]) = pk;
  }
}

// ---------------- fused LN1 + QKV projection ----------------
// block = 128 rows, 4 independent waves x (2 m-tiles). No barriers.
// sched_barrier fences force all 18 weight loads of a group airborne before
// the MFMA block consumes them (vmcnt counts down instead of per-load drain).
__global__ __launch_bounds__(256, 2) void lnqkv_kernel(const float* __restrict__ x,
    const float* __restrict__ g, const float* __restrict__ b,
    const ushort_t* __restrict__ Wt, const float* __restrict__ biasq,
    ushort_t* __restrict__ qkv)
{
  __shared__ ushort_t hbt[128][104];
  int tid = threadIdx.x;
  size_t r0 = (size_t)blockIdx.x * 128;
  ln_to_lds(x + r0 * 96, g, b, hbt, tid);

  int w = tid >> 6, lane = tid & 63, g16 = lane >> 4, l15 = lane & 15;
  short8 af[2][3];
  #pragma unroll
  for (int mi = 0; mi < 2; mi++)
    #pragma unroll
    for (int ks = 0; ks < 3; ks++)
      af[mi][ks] = *reinterpret_cast<const short8*>(&hbt[w * 32 + mi * 16 + l15][ks * 32 + g16 * 8]);

  #pragma unroll
  for (int grp = 0; grp < 3; grp++) {
    short8 wf[18];
    #pragma unroll
    for (int j = 0; j < 6; j++)
      #pragma unroll
      for (int ks = 0; ks < 3; ks++)
        wf[j * 3 + ks] = *reinterpret_cast<const short8*>(
            &Wt[(size_t)((grp * 6 + j) * 16 + l15) * 96 + ks * 32 + g16 * 8]);
    __builtin_amdgcn_sched_barrier(0);   // all 18 loads issued before MFMAs
    f32x4 acc[2][6];
    #pragma unroll
    for (int mi = 0; mi < 2; mi++)
      #pragma unroll
      for (int j = 0; j < 6; j++) acc[mi][j] = (f32x4){0.f, 0.f, 0.f, 0.f};
    #pragma unroll
    for (int j = 0; j < 6; j++)
      #pragma unroll
      for (int ks = 0; ks < 3; ks++) {
        acc[0][j] = __builtin_amdgcn_mfma_f32_16x16x32_bf16(af[0][ks], wf[j * 3 + ks], acc[0][j], 0, 0, 0);
        acc[1][j] = __builtin_amdgcn_mfma_f32_16x16x32_bf16(af[1][ks], wf[j * 3 + ks], acc[1][j], 0, 0, 0);
      }
    #pragma unroll
    for (int j = 0; j < 6; j++) {
      int col = (grp * 6 + j) * 16 + l15;
      float bs = biasq[col];
      #pragma unroll
      for (int mi = 0; mi < 2; mi++)
        #pragma unroll
        for (int r = 0; r < 4; r++)
          qkv[(r0 + w * 32 + mi * 16 + g16 * 4 + r) * 288 + col] = f2bf(acc[mi][j][r] + bs);
    }
  }
}

// ---------------- fused window attention + output projection ----------------
__global__ __launch_bounds__(256) void attn2_kernel(
    const ushort_t* __restrict__ qkv, const ushort_t* __restrict__ Wot,
    const float* __restrict__ bo, const float* __restrict__ xres,
    float* __restrict__ x2)
{
  __shared__ ushort_t Pb[4][64][72];   // P[q][k'] per head
  __shared__ ushort_t Vt[4][32][72];   // V^T[d][k'] per head
  ushort_t (*O_lds)[104] = reinterpret_cast<ushort_t (*)[104]>(&Pb[0][0][0]); // aliases Pb

  int tid = threadIdx.x;
  int h = tid >> 6, lane = tid & 63, g = lane >> 4, l15 = lane & 15;
  int n = blockIdx.x;
  int wq_ = n & 15, hq = (n >> 4) & 15, rest = n >> 8;
  int dq = rest & 7, b = rest >> 3;
  int base = b * 131072 + dq * 16384 + hq * 256 + wq_ * 4;
  #define TOK(s) (base + ((s) >> 4) * 4096 + (((s) >> 2) & 3) * 64 + ((s) & 3))

  {
    int t = TOK(lane);
    const ushort_t* vp = qkv + (size_t)t * 288 + 192 + h * 24;
    short8 v0 = *(const short8*)(vp);
    short8 v1 = *(const short8*)(vp + 8);
    short8 v2 = *(const short8*)(vp + 16);
    #pragma unroll
    for (int d = 0; d < 8; d++) Vt[h][d][lane]      = (ushort_t)v0[d];
    #pragma unroll
    for (int d = 0; d < 8; d++) Vt[h][8 + d][lane]  = (ushort_t)v1[d];
    #pragma unroll
    for (int d = 0; d < 8; d++) Vt[h][16 + d][lane] = (ushort_t)v2[d];
  }

  short8 kf[4], qf[4];
  const short8 z8 = {0, 0, 0, 0, 0, 0, 0, 0};
  #pragma unroll
  for (int i = 0; i < 4; i++) {
    int t = TOK(i * 16 + l15);
    const ushort_t* rp = qkv + (size_t)t * 288 + h * 24 + g * 8;
    qf[i] = (g < 3) ? *(const short8*)(rp)      : z8;
    kf[i] = (g < 3) ? *(const short8*)(rp + 96) : z8;
  }

  f32x4 st[4][4];
  #pragma unroll
  for (int tm = 0; tm < 4; tm++)
    #pragma unroll
    for (int tn = 0; tn < 4; tn++)
      st[tm][tn] = __builtin_amdgcn_mfma_f32_16x16x32_bf16(kf[tm], qf[tn],
                    (f32x4){0.f, 0.f, 0.f, 0.f}, 0, 0, 0);

  const float scale = 0.20412414523193150818f;  // 1/sqrt(24)
  #pragma unroll
  for (int tn = 0; tn < 4; tn++) {
    float m = st[0][tn][0];
    #pragma unroll
    for (int tm = 0; tm < 4; tm++)
      #pragma unroll
      for (int r = 0; r < 4; r++) m = fmaxf(m, st[tm][tn][r]);
    m = fmaxf(m, __shfl_xor(m, 16));
    m = fmaxf(m, __shfl_xor(m, 32));
    float sum = 0.f;
    #pragma unroll
    for (int tm = 0; tm < 4; tm++)
      #pragma unroll
      for (int r = 0; r < 4; r++) {
        float e = __expf((st[tm][tn][r] - m) * scale);
        st[tm][tn][r] = e;
        sum += e;
      }
    sum += __shfl_xor(sum, 16);
    sum += __shfl_xor(sum, 32);
    float inv = 1.0f / sum;
    int q = tn * 16 + l15;
    #pragma unroll
    for (int tm = 0; tm < 4; tm++) {
      unsigned lo = (unsigned)f2bf(st[tm][tn][0] * inv) | ((unsigned)f2bf(st[tm][tn][1] * inv) << 16);
      unsigned hi = (unsigned)f2bf(st[tm][tn][2] * inv) | ((unsigned)f2bf(st[tm][tn][3] * inv) << 16);
      uint2 pk; pk.x = lo; pk.y = hi;
      *(uint2*)&Pb[h][q][tm * 16 + g * 4] = pk;
    }
  }

  f32x4 oacc[4][2];
  #pragma unroll
  for (int qt = 0; qt < 4; qt++)
    #pragma unroll
    for (int dt = 0; dt < 2; dt++) oacc[qt][dt] = (f32x4){0.f, 0.f, 0.f, 0.f};
  #pragma unroll
  for (int ks = 0; ks < 2; ks++) {
    short8 vb[2];
    #pragma unroll
    for (int dt = 0; dt < 2; dt++)
      vb[dt] = *(const short8*)&Vt[h][dt * 16 + l15][ks * 32 + g * 8];
    #pragma unroll
    for (int qt = 0; qt < 4; qt++) {
      short8 pa = *(const short8*)&Pb[h][qt * 16 + l15][ks * 32 + g * 8];
      #pragma unroll
      for (int dt = 0; dt < 2; dt++)
        oacc[qt][dt] = __builtin_amdgcn_mfma_f32_16x16x32_bf16(pa, vb[dt], oacc[qt][dt], 0, 0, 0);
    }
  }

  __syncthreads();
  #pragma unroll
  for (int qt = 0; qt < 4; qt++)
    #pragma unroll
    for (int dt = 0; dt < 2; dt++) {
      int d = dt * 16 + l15;
      if (d < 24) {
        #pragma unroll
        for (int r = 0; r < 4; r++)
          O_lds[qt * 16 + g * 4 + r][h * 24 + d] = f2bf(oacc[qt][dt][r]);
      }
    }
  __syncthreads();

  int w = h;
  f32x4 pacc[6];
  #pragma unroll
  for (int nt = 0; nt < 6; nt++) pacc[nt] = (f32x4){0.f, 0.f, 0.f, 0.f};
  #pragma unroll
  for (int ks = 0; ks < 3; ks++) {
    short8 pa = *(const short8*)&O_lds[w * 16 + l15][ks * 32 + g * 8];
    #pragma unroll
    for (int nt = 0; nt < 6; nt++) {
      short8 wb = *(const short8*)&Wot[(size_t)(nt * 16 + l15) * 96 + ks * 32 + g * 8];
      pacc[nt] = __builtin_amdgcn_mfma_f32_16x16x32_bf16(pa, wb, pacc[nt], 0, 0, 0);
    }
  }
  #pragma unroll
  for (int nt = 0; nt < 6; nt++) {
    int col = nt * 16 + l15;
    float bs = bo[col];
    #pragma unroll
    for (int r = 0; r < 4; r++) {
      int s = w * 16 + g * 4 + r;
      size_t t = (size_t)TOK(s);
      float v = pacc[nt][r] + bs + xres[t * 96 + col];
      x2[t * 96 + col] = v;
    }
  }
  #undef TOK
}

// ---------------- fused LN2 + MLP + residual ----------------
// block = 128 rows, 4 INDEPENDENT waves (wave-private LDS, no barriers;
// mid aliases the LN buffer). sched_barrier fences group the 18-load
// bursts so they stay in flight across the MFMA / gelu phases.
__global__ __launch_bounds__(256, 2) void mlp2_kernel(
    const float* __restrict__ x2, const float* __restrict__ g, const float* __restrict__ b,
    const ushort_t* __restrict__ W1t, const float* __restrict__ b1,
    const ushort_t* __restrict__ W2t, const float* __restrict__ b2,
    float* __restrict__ out)
{
  __shared__ ushort_t smem[128][104];   // LN rows, then mid (same storage)
  int tid = threadIdx.x;
  size_t r0 = (size_t)blockIdx.x * 128;
  ln_to_lds(x2 + r0 * 96, g, b, smem, tid);

  int w = tid >> 6, lane = tid & 63, g16 = lane >> 4, l15 = lane & 15;
  short8 af[2][3];
  #pragma unroll
  for (int mi = 0; mi < 2; mi++)
    #pragma unroll
    for (int ks = 0; ks < 3; ks++)
      af[mi][ks] = *reinterpret_cast<const short8*>(&smem[w * 32 + mi * 16 + l15][ks * 32 + g16 * 8]);

  f32x4 oacc[2][6];
  #pragma unroll
  for (int mi = 0; mi < 2; mi++)
    #pragma unroll
    for (int nt = 0; nt < 6; nt++) oacc[mi][nt] = (f32x4){0.f, 0.f, 0.f, 0.f};

  #pragma unroll
  for (int cc = 0; cc < 4; cc++) {
    // ---- bulk-issue W1 chunk loads ----
    short8 w1f[18];
    #pragma unroll
    for (int j = 0; j < 6; j++)
      #pragma unroll
      for (int ks = 0; ks < 3; ks++)
        w1f[j * 3 + ks] = *reinterpret_cast<const short8*>(
            &W1t[(size_t)(cc * 96 + j * 16 + l15) * 96 + ks * 32 + g16 * 8]);
    __builtin_amdgcn_sched_barrier(0);   // all 18 airborne before phase-1 MFMAs
    // ---- phase 1 MFMAs ----
    f32x4 acc[2][6];
    #pragma unroll
    for (int mi = 0; mi < 2; mi++)
      #pragma unroll
      for (int j = 0; j < 6; j++) acc[mi][j] = (f32x4){0.f, 0.f, 0.f, 0.f};
    #pragma unroll
    for (int j = 0; j < 6; j++)
      #pragma unroll
      for (int ks = 0; ks < 3; ks++) {
        acc[0][j] = __builtin_amdgcn_mfma_f32_16x16x32_bf16(af[0][ks], w1f[j * 3 + ks], acc[0][j], 0, 0, 0);
        acc[1][j] = __builtin_amdgcn_mfma_f32_16x16x32_bf16(af[1][ks], w1f[j * 3 + ks], acc[1][j], 0, 0, 0);
      }
    // ---- issue W2 chunk loads (fly across the gelu phase) ----
    short8 w2f[18];
    #pragma unroll
    for (int j = 0; j < 6; j++)
      #pragma unroll
      for (int ks = 0; ks < 3; ks++)
        w2f[j * 3 + ks] = *reinterpret_cast<const short8*>(
            &W2t[(size_t)(j * 16 + l15) * 384 + cc * 96 + ks * 32 + g16 * 8]);
    __builtin_amdgcn_sched_barrier(0);   // w2f issued above; gelu below
    // ---- gelu + pack to mid (wave-private rows; in-order vs af reads) ----
    #pragma unroll
    for (int j = 0; j < 6; j++) {
      int colg = cc * 96 + j * 16 + l15;
      float bs = b1[colg];
      #pragma unroll
      for (int mi = 0; mi < 2; mi++)
        #pragma unroll
        for (int r = 0; r < 4; r++)
          smem[w * 32 + mi * 16 + g16 * 4 + r][j * 16 + l15] = f2bf(gelu_exact(acc[mi][j][r] + bs));
    }
    // ---- read mid frags (per-wave in-order LDS: sees this wave's writes) ----
    short8 a2[2][3];
    #pragma unroll
    for (int mi = 0; mi < 2; mi++)
      #pragma unroll
      for (int ks = 0; ks < 3; ks++)
        a2[mi][ks] = *reinterpret_cast<const short8*>(&smem[w * 32 + mi * 16 + l15][ks * 32 + g16 * 8]);
    // ---- phase 2 MFMAs ----
    #pragma unroll
    for (int j = 0; j < 6; j++)
      #pragma unroll
      for (int ks = 0; ks < 3; ks++) {
        oacc[0][j] = __builtin_amdgcn_mfma_f32_16x16x32_bf16(a2[0][ks], w2f[j * 3 + ks], oacc[0][j], 0, 0, 0);
        oacc[1][j] = __builtin_amdgcn_mfma_f32_16x16x32_bf16(a2[1][ks], w2f[j * 3 + ks], oacc[1][j], 0, 0, 0);
      }
  }

  // epilogue: out = oacc + b2 + residual(x2)
  #pragma unroll
  for (int j = 0; j < 6; j++) {
    int col = j * 16 + l15;
    float bs = b2[col];
    #pragma unroll
    for (int mi = 0; mi < 2; mi++)
      #pragma unroll
      for (int r = 0; r < 4; r++) {
        size_t row = r0 + w * 32 + mi * 16 + g16 * 4 + r;
        out[row * 96 + col] = oacc[mi][j][r] + bs + x2[row * 96 + col];
      }
  }
}

// ---------------- launch ----------------
extern "C" void kernel_launch(void* const* d_in, const int* in_sizes, int n_in,
                              void* d_out, int out_size, void* d_ws, size_t ws_size,
                              hipStream_t stream)
{
  (void)in_sizes; (void)n_in; (void)out_size; (void)ws_size;
  const float* x    = (const float*)d_in[0];
  const float* ln1g = (const float*)d_in[1];
  const float* ln1b = (const float*)d_in[2];
  const float* wq   = (const float*)d_in[3];
  const float* bq   = (const float*)d_in[4];
  const float* wk   = (const float*)d_in[5];
  const float* bk   = (const float*)d_in[6];
  const float* wv   = (const float*)d_in[7];
  const float* bv   = (const float*)d_in[8];
  const float* wo   = (const float*)d_in[9];
  const float* bo   = (const float*)d_in[10];
  const float* ln2g = (const float*)d_in[11];
  const float* ln2b = (const float*)d_in[12];
  const float* w1   = (const float*)d_in[13];
  const float* b1   = (const float*)d_in[14];
  const float* w2   = (const float*)d_in[15];
  const float* b2   = (const float*)d_in[16];

  char* ws = (char*)d_ws;
  ushort_t* qkv  = (ushort_t*)(ws);                          // [N,288] bf16  150,994,944 B
  char* wsw      = ws + 150994944;
  ushort_t* Wqkv = (ushort_t*)(wsw);                         // [288][96]
  ushort_t* Wo   = (ushort_t*)(wsw + 55296);                 // [96][96]
  ushort_t* W1   = (ushort_t*)(wsw + 55296 + 18432);         // [384][96]
  ushort_t* W2   = (ushort_t*)(wsw + 55296 + 18432 + 73728); // [96][384]
  float*    biasq= (float*)   (wsw + 55296 + 18432 + 73728 + 73728); // [288] fp32
  float* x2 = (float*)d_out;   // post-attention residual lives in d_out

  prep_kernel<<<434, 256, 0, stream>>>(wq, wk, wv, wo, w1, w2, bq, bk, bv,
                                       Wqkv, Wo, W1, W2, biasq);
  lnqkv_kernel<<<NTOK / 128, 256, 0, stream>>>(x, ln1g, ln1b, Wqkv, biasq, qkv);
  attn2_kernel<<<4096, 256, 0, stream>>>(qkv, Wo, bo, x, x2);
  mlp2_kernel<<<NTOK / 128, 256, 0, stream>>>(x2, ln2g, ln2b, W1, b1, W2, b2, (float*)d_out);
}

// Round 8
// 288.474 us; speedup vs baseline: 1.1427x; 1.1092x over previous
//
#include <hip/hip_runtime.h>
#include <hip/hip_bf16.h>

typedef __attribute__((ext_vector_type(8))) short short8;
typedef __attribute__((ext_vector_type(4))) float f32x4;
typedef unsigned short ushort_t;

#define NTOK 262144   // B*D*H*W = 2*32*64*64

__device__ __forceinline__ ushort_t f2bf(float f){
  unsigned int x = __float_as_uint(f);
  unsigned int r = (x + 0x7fffu + ((x >> 16) & 1u)) >> 16;
  return (ushort_t)r;
}
// exact-erf gelu via Abramowitz-Stegun 7.1.26 (|err| <= 1.5e-7), branch-free
__device__ __forceinline__ float gelu_exact(float x){
  float u = fabsf(x) * 0.70710678118654752440f;
  float t = 1.0f / (1.0f + 0.3275911f * u);
  float poly = t * (0.254829592f + t * (-0.284496736f + t * (1.421413741f +
               t * (-1.453152027f + t * 1.061405429f))));
  float e = __expf(-u * u);
  float er = copysignf(1.0f - poly * e, x);
  return 0.5f * x * (1.0f + er);
}
// LDS-only barrier: drains lgkm (my ds reads/writes done) but NOT vmcnt.
__device__ __forceinline__ void bar_lds(){
  asm volatile("s_waitcnt lgkmcnt(0)" ::: "memory");
  __builtin_amdgcn_s_barrier();
}
// async global->LDS, 16B per lane; LDS dest = wave-uniform base + lane*16
__device__ __forceinline__ void gl_lds16(const ushort_t* g, ushort_t* l){
  __builtin_amdgcn_global_load_lds(
      (const __attribute__((address_space(1))) void*)g,
      (__attribute__((address_space(3))) void*)l, 16, 0, 0);
}

// Stage a [96][96]-bf16 weight slice (global row stride src_stride) into a
// padded LDS tile [96][104]. 13 x 16B units per LDS row: units 0..11 = data,
// unit 12 lands in the pad (source = row start, garbage, never read).
// LDS fill is LINEAR (unit u -> byte u*16); the pad skip is encoded in the
// per-lane SOURCE address (global_load_lds dest must be linear in lane).
__device__ __forceinline__ void stage_w(const ushort_t* __restrict__ src,
                                        int src_stride, ushort_t (*dst)[104], int tid)
{
  #pragma unroll
  for (int it = 0; it < 5; ++it) {
    int u = tid + it * 256;
    if (u < 1248) {
      int row = u / 13, c16 = u % 13;
      const ushort_t* sp = src + row * src_stride + ((c16 == 12) ? 0 : c16 * 8);
      gl_lds16(sp, &dst[0][0] + (size_t)(u & ~63) * 8);
    }
  }
}

// ---------------- weight prep: fp32 -> bf16, transposed to Bt[col][k] ----------------
__global__ __launch_bounds__(256) void prep_kernel(
    const float* __restrict__ wq, const float* __restrict__ wk, const float* __restrict__ wv,
    const float* __restrict__ wo, const float* __restrict__ w1, const float* __restrict__ w2,
    const float* __restrict__ bq, const float* __restrict__ bk, const float* __restrict__ bv,
    ushort_t* __restrict__ Wqkv, ushort_t* __restrict__ Wo,
    ushort_t* __restrict__ W1, ushort_t* __restrict__ W2, float* __restrict__ biasq)
{
  int i = blockIdx.x * 256 + threadIdx.x;
  if (i < 27648) {                       // Wqkv_t[j][c], j = s*96 + h*24 + d
    int j = i / 96, c = i % 96;
    int s = j / 96, rem = j % 96;
    const float* src = (s == 0) ? wq : (s == 1) ? wk : wv;
    Wqkv[j * 96 + c] = f2bf(src[c * 96 + rem]);
  } else if (i < 36864) {                // Wo_t[c][hd] = wo[hd][c]
    int ii = i - 27648;
    int c = ii / 96, hd = ii % 96;
    Wo[ii] = f2bf(wo[hd * 96 + c]);
  } else if (i < 73728) {                // W1_t[j][c] = w1[c][j]
    int ii = i - 36864;
    int j = ii / 96, c = ii % 96;
    W1[ii] = f2bf(w1[c * 384 + j]);
  } else if (i < 110592) {               // W2_t[c][j] = w2[j][c]
    int ii = i - 73728;
    int c = ii / 384, j = ii % 384;
    W2[ii] = f2bf(w2[j * 96 + c]);
  } else if (i < 110880) {               // combined qkv bias (fp32)
    int j = i - 110592;
    int s = j / 96, rem = j % 96;
    const float* src = (s == 0) ? bq : (s == 1) ? bk : bv;
    biasq[j] = src[rem];
  }
}

// ---- per-thread half-row LN into LDS tile smem[128][104] (bf16) ----
__device__ __forceinline__ void ln_to_lds(const float* __restrict__ xrow_base,
    const float* __restrict__ gg, const float* __restrict__ bb,
    ushort_t (*hbt)[104], int tid)
{
  int row = tid >> 1, half = tid & 1;
  const float* xp = xrow_base + (size_t)row * 96 + half * 48;
  f32x4 v[12];
  float s = 0.f, sq = 0.f;
  #pragma unroll
  for (int i = 0; i < 12; i++) {
    v[i] = *reinterpret_cast<const f32x4*>(xp + i * 4);
    #pragma unroll
    for (int j = 0; j < 4; j++) { s += v[i][j]; sq += v[i][j] * v[i][j]; }
  }
  s  += __shfl_xor(s, 1);
  sq += __shfl_xor(sq, 1);
  float mean = s * (1.0f / 96.0f);
  float var  = sq * (1.0f / 96.0f) - mean * mean;
  float rstd = rsqrtf(var + 1e-5f);
  #pragma unroll
  for (int i8 = 0; i8 < 6; i8++) {
    short8 pk;
    #pragma unroll
    for (int j = 0; j < 8; j++) {
      int c = half * 48 + i8 * 8 + j;
      pk[j] = (short)f2bf((v[(i8 * 8 + j) >> 2][(i8 * 8 + j) & 3] - mean) * rstd * gg[c] + bb[c]);
    }
    *reinterpret_cast<short8*>(&hbt[row][half * 48 + i8 * 8]) = pk;
  }
}

// ---------------- fused LN1 + QKV projection ----------------
// block = 128 rows, 4 waves. Weight slices staged block-wide into LDS once
// per 96-col group (global_load_lds); MFMAs read weights from LDS.
__global__ __launch_bounds__(256, 3) void lnqkv_kernel(const float* __restrict__ x,
    const float* __restrict__ g, const float* __restrict__ b,
    const ushort_t* __restrict__ Wt, const float* __restrict__ biasq,
    ushort_t* __restrict__ qkv)
{
  __shared__ ushort_t hbt[128][104];   // 26.6 KB
  __shared__ ushort_t Ws[96][104];     // 20 KB -> 46.6 KB total, 3 blocks/CU
  int tid = threadIdx.x;
  size_t r0 = (size_t)blockIdx.x * 128;

  stage_w(Wt, 96, Ws, tid);            // group 0 slice in flight under LN
  ln_to_lds(x + r0 * 96, g, b, hbt, tid);
  __syncthreads();                     // stage-0 + LN LDS visible

  int w = tid >> 6, lane = tid & 63, g16 = lane >> 4, l15 = lane & 15;
  short8 af[2][3];
  #pragma unroll
  for (int mi = 0; mi < 2; mi++)
    #pragma unroll
    for (int ks = 0; ks < 3; ks++)
      af[mi][ks] = *reinterpret_cast<const short8*>(&hbt[w * 32 + mi * 16 + l15][ks * 32 + g16 * 8]);

  for (int grp = 0; grp < 3; ++grp) {
    f32x4 acc[2][6];
    #pragma unroll
    for (int mi = 0; mi < 2; mi++)
      #pragma unroll
      for (int j = 0; j < 6; j++) acc[mi][j] = (f32x4){0.f, 0.f, 0.f, 0.f};
    #pragma unroll
    for (int j = 0; j < 6; j++)
      #pragma unroll
      for (int ks = 0; ks < 3; ks++) {
        short8 wfr = *reinterpret_cast<const short8*>(&Ws[j * 16 + l15][ks * 32 + g16 * 8]);
        acc[0][j] = __builtin_amdgcn_mfma_f32_16x16x32_bf16(af[0][ks], wfr, acc[0][j], 0, 0, 0);
        acc[1][j] = __builtin_amdgcn_mfma_f32_16x16x32_bf16(af[1][ks], wfr, acc[1][j], 0, 0, 0);
      }
    #pragma unroll
    for (int j = 0; j < 6; j++) {
      int col = grp * 96 + j * 16 + l15;
      float bs = biasq[col];
      #pragma unroll
      for (int mi = 0; mi < 2; mi++)
        #pragma unroll
        for (int r = 0; r < 4; r++)
          qkv[(r0 + w * 32 + mi * 16 + g16 * 4 + r) * 288 + col] = f2bf(acc[mi][j][r] + bs);
    }
    bar_lds();                          // all waves done reading Ws
    if (grp < 2) {
      stage_w(Wt + (grp + 1) * 96 * 96, 96, Ws, tid);
      __syncthreads();                  // staged slice visible
    }
  }
}

// ---------------- fused window attention + output projection ----------------
__global__ __launch_bounds__(256) void attn2_kernel(
    const ushort_t* __restrict__ qkv, const ushort_t* __restrict__ Wot,
    const float* __restrict__ bo, const float* __restrict__ xres,
    float* __restrict__ x2)
{
  __shared__ ushort_t Pb[4][64][72];   // P[q][k'] per head
  __shared__ ushort_t Vt[4][32][72];   // V^T[d][k'] per head
  ushort_t (*O_lds)[104] = reinterpret_cast<ushort_t (*)[104]>(&Pb[0][0][0]); // aliases Pb

  int tid = threadIdx.x;
  int h = tid >> 6, lane = tid & 63, g = lane >> 4, l15 = lane & 15;
  int n = blockIdx.x;
  int wq_ = n & 15, hq = (n >> 4) & 15, rest = n >> 8;
  int dq = rest & 7, b = rest >> 3;
  int base = b * 131072 + dq * 16384 + hq * 256 + wq_ * 4;
  #define TOK(s) (base + ((s) >> 4) * 4096 + (((s) >> 2) & 3) * 64 + ((s) & 3))

  {
    int t = TOK(lane);
    const ushort_t* vp = qkv + (size_t)t * 288 + 192 + h * 24;
    short8 v0 = *(const short8*)(vp);
    short8 v1 = *(const short8*)(vp + 8);
    short8 v2 = *(const short8*)(vp + 16);
    #pragma unroll
    for (int d = 0; d < 8; d++) Vt[h][d][lane]      = (ushort_t)v0[d];
    #pragma unroll
    for (int d = 0; d < 8; d++) Vt[h][8 + d][lane]  = (ushort_t)v1[d];
    #pragma unroll
    for (int d = 0; d < 8; d++) Vt[h][16 + d][lane] = (ushort_t)v2[d];
  }

  short8 kf[4], qf[4];
  const short8 z8 = {0, 0, 0, 0, 0, 0, 0, 0};
  #pragma unroll
  for (int i = 0; i < 4; i++) {
    int t = TOK(i * 16 + l15);
    const ushort_t* rp = qkv + (size_t)t * 288 + h * 24 + g * 8;
    qf[i] = (g < 3) ? *(const short8*)(rp)      : z8;
    kf[i] = (g < 3) ? *(const short8*)(rp + 96) : z8;
  }

  f32x4 st[4][4];
  #pragma unroll
  for (int tm = 0; tm < 4; tm++)
    #pragma unroll
    for (int tn = 0; tn < 4; tn++)
      st[tm][tn] = __builtin_amdgcn_mfma_f32_16x16x32_bf16(kf[tm], qf[tn],
                    (f32x4){0.f, 0.f, 0.f, 0.f}, 0, 0, 0);

  const float scale = 0.20412414523193150818f;  // 1/sqrt(24)
  #pragma unroll
  for (int tn = 0; tn < 4; tn++) {
    float m = st[0][tn][0];
    #pragma unroll
    for (int tm = 0; tm < 4; tm++)
      #pragma unroll
      for (int r = 0; r < 4; r++) m = fmaxf(m, st[tm][tn][r]);
    m = fmaxf(m, __shfl_xor(m, 16));
    m = fmaxf(m, __shfl_xor(m, 32));
    float sum = 0.f;
    #pragma unroll
    for (int tm = 0; tm < 4; tm++)
      #pragma unroll
      for (int r = 0; r < 4; r++) {
        float e = __expf((st[tm][tn][r] - m) * scale);
        st[tm][tn][r] = e;
        sum += e;
      }
    sum += __shfl_xor(sum, 16);
    sum += __shfl_xor(sum, 32);
    float inv = 1.0f / sum;
    int q = tn * 16 + l15;
    #pragma unroll
    for (int tm = 0; tm < 4; tm++) {
      unsigned lo = (unsigned)f2bf(st[tm][tn][0] * inv) | ((unsigned)f2bf(st[tm][tn][1] * inv) << 16);
      unsigned hi = (unsigned)f2bf(st[tm][tn][2] * inv) | ((unsigned)f2bf(st[tm][tn][3] * inv) << 16);
      uint2 pk; pk.x = lo; pk.y = hi;
      *(uint2*)&Pb[h][q][tm * 16 + g * 4] = pk;
    }
  }

  f32x4 oacc[4][2];
  #pragma unroll
  for (int qt = 0; qt < 4; qt++)
    #pragma unroll
    for (int dt = 0; dt < 2; dt++) oacc[qt][dt] = (f32x4){0.f, 0.f, 0.f, 0.f};
  #pragma unroll
  for (int ks = 0; ks < 2; ks++) {
    short8 vb[2];
    #pragma unroll
    for (int dt = 0; dt < 2; dt++)
      vb[dt] = *(const short8*)&Vt[h][dt * 16 + l15][ks * 32 + g * 8];
    #pragma unroll
    for (int qt = 0; qt < 4; qt++) {
      short8 pa = *(const short8*)&Pb[h][qt * 16 + l15][ks * 32 + g * 8];
      #pragma unroll
      for (int dt = 0; dt < 2; dt++)
        oacc[qt][dt] = __builtin_amdgcn_mfma_f32_16x16x32_bf16(pa, vb[dt], oacc[qt][dt], 0, 0, 0);
    }
  }

  __syncthreads();
  #pragma unroll
  for (int qt = 0; qt < 4; qt++)
    #pragma unroll
    for (int dt = 0; dt < 2; dt++) {
      int d = dt * 16 + l15;
      if (d < 24) {
        #pragma unroll
        for (int r = 0; r < 4; r++)
          O_lds[qt * 16 + g * 4 + r][h * 24 + d] = f2bf(oacc[qt][dt][r]);
      }
    }
  __syncthreads();

  int w = h;
  f32x4 pacc[6];
  #pragma unroll
  for (int nt = 0; nt < 6; nt++) pacc[nt] = (f32x4){0.f, 0.f, 0.f, 0.f};
  #pragma unroll
  for (int ks = 0; ks < 3; ks++) {
    short8 pa = *(const short8*)&O_lds[w * 16 + l15][ks * 32 + g * 8];
    #pragma unroll
    for (int nt = 0; nt < 6; nt++) {
      short8 wb = *(const short8*)&Wot[(size_t)(nt * 16 + l15) * 96 + ks * 32 + g * 8];
      pacc[nt] = __builtin_amdgcn_mfma_f32_16x16x32_bf16(pa, wb, pacc[nt], 0, 0, 0);
    }
  }
  #pragma unroll
  for (int nt = 0; nt < 6; nt++) {
    int col = nt * 16 + l15;
    float bs = bo[col];
    #pragma unroll
    for (int r = 0; r < 4; r++) {
      int s = w * 16 + g * 4 + r;
      size_t t = (size_t)TOK(s);
      float v = pacc[nt][r] + bs + xres[t * 96 + col];
      x2[t * 96 + col] = v;
    }
  }
  #undef TOK
}

// ---------------- fused LN2 + MLP + residual ----------------
// block = 128 rows, 4 waves. Per 96-col chunk: W1/W2 slices staged block-wide
// into LDS (global_load_lds), MFMAs read from LDS. mid aliases the LN buffer
// (wave-private rows). LDS 66.6 KB -> 2 blocks/CU.
__global__ __launch_bounds__(256, 2) void mlp2_kernel(
    const float* __restrict__ x2, const float* __restrict__ g, const float* __restrict__ b,
    const ushort_t* __restrict__ W1t, const float* __restrict__ b1,
    const ushort_t* __restrict__ W2t, const float* __restrict__ b2,
    float* __restrict__ out)
{
  __shared__ ushort_t smem[128][104];  // LN rows, then mid (same storage)
  __shared__ ushort_t W1s[96][104];
  __shared__ ushort_t W2s[96][104];
  int tid = threadIdx.x;
  size_t r0 = (size_t)blockIdx.x * 128;

  stage_w(W1t, 96, W1s, tid);          // chunk-0 slices in flight under LN
  stage_w(W2t, 384, W2s, tid);
  ln_to_lds(x2 + r0 * 96, g, b, smem, tid);
  __syncthreads();

  int w = tid >> 6, lane = tid & 63, g16 = lane >> 4, l15 = lane & 15;
  short8 af[2][3];
  #pragma unroll
  for (int mi = 0; mi < 2; mi++)
    #pragma unroll
    for (int ks = 0; ks < 3; ks++)
      af[mi][ks] = *reinterpret_cast<const short8*>(&smem[w * 32 + mi * 16 + l15][ks * 32 + g16 * 8]);

  f32x4 oacc[2][6];
  #pragma unroll
  for (int mi = 0; mi < 2; mi++)
    #pragma unroll
    for (int nt = 0; nt < 6; nt++) oacc[mi][nt] = (f32x4){0.f, 0.f, 0.f, 0.f};

  for (int cc = 0; cc < 4; ++cc) {
    // ---- phase 1: mid chunk = gelu(hbt @ W1slice + b1) ----
    f32x4 acc[2][6];
    #pragma unroll
    for (int mi = 0; mi < 2; mi++)
      #pragma unroll
      for (int j = 0; j < 6; j++) acc[mi][j] = (f32x4){0.f, 0.f, 0.f, 0.f};
    #pragma unroll
    for (int j = 0; j < 6; j++)
      #pragma unroll
      for (int ks = 0; ks < 3; ks++) {
        short8 wfr = *reinterpret_cast<const short8*>(&W1s[j * 16 + l15][ks * 32 + g16 * 8]);
        acc[0][j] = __builtin_amdgcn_mfma_f32_16x16x32_bf16(af[0][ks], wfr, acc[0][j], 0, 0, 0);
        acc[1][j] = __builtin_amdgcn_mfma_f32_16x16x32_bf16(af[1][ks], wfr, acc[1][j], 0, 0, 0);
      }
    #pragma unroll
    for (int j = 0; j < 6; j++) {
      int colg = cc * 96 + j * 16 + l15;
      float bs = b1[colg];
      #pragma unroll
      for (int mi = 0; mi < 2; mi++)
        #pragma unroll
        for (int r = 0; r < 4; r++)
          smem[w * 32 + mi * 16 + g16 * 4 + r][j * 16 + l15] = f2bf(gelu_exact(acc[mi][j][r] + bs));
    }
    // ---- read mid frags (wave-private rows, per-wave in-order LDS) ----
    short8 a2[2][3];
    #pragma unroll
    for (int mi = 0; mi < 2; mi++)
      #pragma unroll
      for (int ks = 0; ks < 3; ks++)
        a2[mi][ks] = *reinterpret_cast<const short8*>(&smem[w * 32 + mi * 16 + l15][ks * 32 + g16 * 8]);
    // ---- phase 2: oacc += mid_chunk @ W2slice ----
    #pragma unroll
    for (int j = 0; j < 6; j++)
      #pragma unroll
      for (int ks = 0; ks < 3; ks++) {
        short8 wfr = *reinterpret_cast<const short8*>(&W2s[j * 16 + l15][ks * 32 + g16 * 8]);
        oacc[0][j] = __builtin_amdgcn_mfma_f32_16x16x32_bf16(a2[0][ks], wfr, oacc[0][j], 0, 0, 0);
        oacc[1][j] = __builtin_amdgcn_mfma_f32_16x16x32_bf16(a2[1][ks], wfr, oacc[1][j], 0, 0, 0);
      }
    bar_lds();                          // all waves done reading W1s/W2s
    if (cc < 3) {
      stage_w(W1t + (cc + 1) * 96 * 96, 96, W1s, tid);
      stage_w(W2t + (cc + 1) * 96, 384, W2s, tid);
      __syncthreads();                  // staged slices visible
    }
  }

  // epilogue: out = oacc + b2 + residual(x2)
  #pragma unroll
  for (int j = 0; j < 6; j++) {
    int col = j * 16 + l15;
    float bs = b2[col];
    #pragma unroll
    for (int mi = 0; mi < 2; mi++)
      #pragma unroll
      for (int r = 0; r < 4; r++) {
        size_t row = r0 + w * 32 + mi * 16 + g16 * 4 + r;
        out[row * 96 + col] = oacc[mi][j][r] + bs + x2[row * 96 + col];
      }
  }
}

// ---------------- launch ----------------
extern "C" void kernel_launch(void* const* d_in, const int* in_sizes, int n_in,
                              void* d_out, int out_size, void* d_ws, size_t ws_size,
                              hipStream_t stream)
{
  (void)in_sizes; (void)n_in; (void)out_size; (void)ws_size;
  const float* x    = (const float*)d_in[0];
  const float* ln1g = (const float*)d_in[1];
  const float* ln1b = (const float*)d_in[2];
  const float* wq   = (const float*)d_in[3];
  const float* bq   = (const float*)d_in[4];
  const float* wk   = (const float*)d_in[5];
  const float* bk   = (const float*)d_in[6];
  const float* wv   = (const float*)d_in[7];
  const float* bv   = (const float*)d_in[8];
  const float* wo   = (const float*)d_in[9];
  const float* bo   = (const float*)d_in[10];
  const float* ln2g = (const float*)d_in[11];
  const float* ln2b = (const float*)d_in[12];
  const float* w1   = (const float*)d_in[13];
  const float* b1   = (const float*)d_in[14];
  const float* w2   = (const float*)d_in[15];
  const float* b2   = (const float*)d_in[16];

  char* ws = (char*)d_ws;
  ushort_t* qkv  = (ushort_t*)(ws);                          // [N,288] bf16  150,994,944 B
  char* wsw      = ws + 150994944;
  ushort_t* Wqkv = (ushort_t*)(wsw);                         // [288][96]
  ushort_t* Wo   = (ushort_t*)(wsw + 55296);                 // [96][96]
  ushort_t* W1   = (ushort_t*)(wsw + 55296 + 18432);         // [384][96]
  ushort_t* W2   = (ushort_t*)(wsw + 55296 + 18432 + 73728); // [96][384]
  float*    biasq= (float*)   (wsw + 55296 + 18432 + 73728 + 73728); // [288] fp32
  float* x2 = (float*)d_out;   // post-attention residual lives in d_out

  prep_kernel<<<434, 256, 0, stream>>>(wq, wk, wv, wo, w1, w2, bq, bk, bv,
                                       Wqkv, Wo, W1, W2, biasq);
  lnqkv_kernel<<<NTOK / 128, 256, 0, stream>>>(x, ln1g, ln1b, Wqkv, biasq, qkv);
  attn2_kernel<<<4096, 256, 0, stream>>>(qkv, Wo, bo, x, x2);
  mlp2_kernel<<<NTOK / 128, 256, 0, stream>>>(x2, ln2g, ln2b, W1, b1, W2, b2, (float*)d_out);
}